// Round 2
// baseline (445.371 us; speedup 1.0000x reference)
//
#include <hip/hip_runtime.h>
#include <stdint.h>

#define NB 64
#define NR 1152
#define NI 64
#define NC 32
#define NO 32

// ---------------------------------------------------------------------------
// K1: priors[cl,b,r,o] = sum_i x[b,r,i] * W[c0+cl,r,i,o], fp32 out.
// grid (nc, NR/2), block 128 (2 waves, 1 r per wave).
// Wave layout: lane = bq*4 + og; thread tile = 4 b x 8 o (acc 32 VGPR).
// x: LDS transposed [i][b] with XOR swizzle (conflict-free ds_read_b128).
// W: streamed from global (2x dwordx4 per i), no LDS broadcast waste.
// ---------------------------------------------------------------------------
__global__ __launch_bounds__(128, 4)
void k_priors(const float* __restrict__ x, const float* __restrict__ W,
              float* __restrict__ P, int c0) {
  __shared__ float xs[2][NI][68];   // [wave][i][b swizzled], 68 stride: 16B-aligned rows
  const int tid  = threadIdx.x;
  const int lane = tid & 63;
  const int w    = tid >> 6;
  const int cl   = blockIdx.x;
  const int c    = c0 + cl;
  const int r    = blockIdx.y * 2 + w;
  const int og   = lane & 3;        // o-oct: o = og*8 + 0..7
  const int bq   = lane >> 2;       // b-quad: b = bq*4 + 0..3

  // stage x[.][r][.] -> xs[w][i][b ^ key(i)]  (key(i) = ((i>>1)&7)*4)
  {
    const int i0   = (lane & 15) * 4;
    const int brow = lane >> 4;
#pragma unroll
    for (int kk = 0; kk < 16; ++kk) {
      const int b = brow + kk * 4;
      const float4 v = *reinterpret_cast<const float4*>(
          x + ((size_t)b * NR + r) * NI + i0);
      xs[w][i0 + 0][b ^ ((((i0 + 0) >> 1) & 7) * 4)] = v.x;
      xs[w][i0 + 1][b ^ ((((i0 + 1) >> 1) & 7) * 4)] = v.y;
      xs[w][i0 + 2][b ^ ((((i0 + 2) >> 1) & 7) * 4)] = v.z;
      xs[w][i0 + 3][b ^ ((((i0 + 3) >> 1) & 7) * 4)] = v.w;
    }
  }
  __syncthreads();

  float acc[4][8];
#pragma unroll
  for (int a = 0; a < 4; ++a)
#pragma unroll
    for (int q = 0; q < 8; ++q) acc[a][q] = 0.f;

  const float* Wr = W + ((size_t)c * NR + r) * (NI * NO) + og * 8;

#pragma unroll 4
  for (int i = 0; i < NI; ++i) {
    const int key = ((i >> 1) & 7) * 4;
    const float4 xv = *reinterpret_cast<const float4*>(&xs[w][i][(bq * 4) ^ key]);
    const float4 w0 = *reinterpret_cast<const float4*>(Wr + i * NO);
    const float4 w1 = *reinterpret_cast<const float4*>(Wr + i * NO + 4);
    const float xa[4] = {xv.x, xv.y, xv.z, xv.w};
    const float wv[8] = {w0.x, w0.y, w0.z, w0.w, w1.x, w1.y, w1.z, w1.w};
#pragma unroll
    for (int a = 0; a < 4; ++a)
#pragma unroll
      for (int q = 0; q < 8; ++q)
        acc[a][q] = fmaf(xa[a], wv[q], acc[a][q]);
  }

#pragma unroll
  for (int a = 0; a < 4; ++a) {
    const int b = bq * 4 + a;
    float* dst = P + (((size_t)cl * NB + b) * NR + r) * NO + og * 8;
    *reinterpret_cast<float4*>(dst)     = make_float4(acc[a][0], acc[a][1], acc[a][2], acc[a][3]);
    *reinterpret_cast<float4*>(dst + 4) = make_float4(acc[a][4], acc[a][5], acc[a][6], acc[a][7]);
  }
}

// ---------------------------------------------------------------------------
// K2: full 3-iteration routing for one (c,b). block 512 (8 waves).
// 8 lanes per route-row (sl = o-slice of 4); P slice lives in registers
// (p[18] float4 per thread), read from global EXACTLY once, coalesced 1KB/instr.
// ---------------------------------------------------------------------------
__device__ __forceinline__ void merge4(float& m, float& Z, float4& T,
                                       float m2, float Z2, const float4& T2) {
  const float mn = fmaxf(m, m2);
  const float a1 = __expf(m - mn), a2 = __expf(m2 - mn);
  Z   = Z * a1 + Z2 * a2;
  T.x = T.x * a1 + T2.x * a2;
  T.y = T.y * a1 + T2.y * a2;
  T.z = T.z * a1 + T2.z * a2;
  T.w = T.w * a1 + T2.w * a2;
  m = mn;
}

__global__ __launch_bounds__(512, 4)
void k_route(const float* __restrict__ P, float* __restrict__ out, int c0) {
  __shared__ float red_s[8][8][8];  // [wave][slice][m,Z,T0..3,pad]
  __shared__ float u_s[NO];

  const int tid  = threadIdx.x;
  const int lane = tid & 63;
  const int wave = tid >> 6;
  const int sl   = tid & 7;   // o-slice: o = sl*4 + 0..3
  const int grp  = tid >> 3;  // row group 0..63; rows r = grp + 64*j
  const int b    = blockIdx.x;
  const int cl   = blockIdx.y;
  const int c    = c0 + cl;
  const float* Pb = P + ((size_t)cl * NB + b) * ((size_t)NR * NO);

  float4 p[18];
#pragma unroll
  for (int j = 0; j < 18; ++j)
    p[j] = *reinterpret_cast<const float4*>(Pb + (size_t)(grp + 64 * j) * NO + sl * 4);

  // ---- iteration 0: uniform softmax -> S0 = mean_r p ----
  float4 T = p[0];
#pragma unroll
  for (int j = 1; j < 18; ++j) {
    T.x += p[j].x; T.y += p[j].y; T.z += p[j].z; T.w += p[j].w;
  }
#pragma unroll
  for (int off = 8; off <= 32; off <<= 1) {
    T.x += __shfl_xor(T.x, off); T.y += __shfl_xor(T.y, off);
    T.z += __shfl_xor(T.z, off); T.w += __shfl_xor(T.w, off);
  }
  if (lane < 8) {
    red_s[wave][sl][2] = T.x; red_s[wave][sl][3] = T.y;
    red_s[wave][sl][4] = T.z; red_s[wave][sl][5] = T.w;
  }
  __syncthreads();
  if (wave == 0) {
    const int ww = lane >> 3, ss = lane & 7;
    float4 S;
    S.x = red_s[ww][ss][2]; S.y = red_s[ww][ss][3];
    S.z = red_s[ww][ss][4]; S.w = red_s[ww][ss][5];
#pragma unroll
    for (int off = 8; off <= 32; off <<= 1) {
      S.x += __shfl_xor(S.x, off); S.y += __shfl_xor(S.y, off);
      S.z += __shfl_xor(S.z, off); S.w += __shfl_xor(S.w, off);
    }
    S.x *= (1.f / NR); S.y *= (1.f / NR); S.z *= (1.f / NR); S.w *= (1.f / NR);
    float n2 = S.x * S.x + S.y * S.y + S.z * S.z + S.w * S.w;
    n2 += __shfl_xor(n2, 1); n2 += __shfl_xor(n2, 2); n2 += __shfl_xor(n2, 4);
    const float scale = n2 / ((1.f + n2) * sqrtf(n2));
    if (lane < 8) {
      u_s[ss * 4 + 0] = S.x * scale; u_s[ss * 4 + 1] = S.y * scale;
      u_s[ss * 4 + 2] = S.z * scale; u_s[ss * 4 + 3] = S.w * scale;
    }
  }
  __syncthreads();

  float4 u = *reinterpret_cast<const float4*>(&u_s[sl * 4]);
  float l1[18];

  for (int it = 1; it <= 2; ++it) {
    float m = -3.0e38f, Z = 0.f;
    T = make_float4(0.f, 0.f, 0.f, 0.f);
#pragma unroll
    for (int j = 0; j < 18; ++j) {
      float d = p[j].x * u.x + p[j].y * u.y + p[j].z * u.z + p[j].w * u.w;
      d += __shfl_xor(d, 1); d += __shfl_xor(d, 2); d += __shfl_xor(d, 4);
      float l;
      if (it == 1) { l1[j] = d; l = d; }
      else         { l = l1[j] + d; }
      const float mn = fmaxf(m, l);
      const float a = __expf(m - mn);  // rescale old state (0 on first step)
      const float e = __expf(l - mn);
      Z   = Z * a + e;
      T.x = T.x * a + e * p[j].x; T.y = T.y * a + e * p[j].y;
      T.z = T.z * a + e * p[j].z; T.w = T.w * a + e * p[j].w;
      m = mn;
    }
#pragma unroll
    for (int off = 8; off <= 32; off <<= 1) {
      const float m2 = __shfl_xor(m, off);
      const float Z2 = __shfl_xor(Z, off);
      float4 T2;
      T2.x = __shfl_xor(T.x, off); T2.y = __shfl_xor(T.y, off);
      T2.z = __shfl_xor(T.z, off); T2.w = __shfl_xor(T.w, off);
      merge4(m, Z, T, m2, Z2, T2);
    }
    if (lane < 8) {
      red_s[wave][sl][0] = m;   red_s[wave][sl][1] = Z;
      red_s[wave][sl][2] = T.x; red_s[wave][sl][3] = T.y;
      red_s[wave][sl][4] = T.z; red_s[wave][sl][5] = T.w;
    }
    __syncthreads();
    if (wave == 0) {
      const int ww = lane >> 3, ss = lane & 7;
      float mm = red_s[ww][ss][0], ZZ = red_s[ww][ss][1];
      float4 TT;
      TT.x = red_s[ww][ss][2]; TT.y = red_s[ww][ss][3];
      TT.z = red_s[ww][ss][4]; TT.w = red_s[ww][ss][5];
#pragma unroll
      for (int off = 8; off <= 32; off <<= 1) {
        const float m2 = __shfl_xor(mm, off);
        const float Z2 = __shfl_xor(ZZ, off);
        float4 T2;
        T2.x = __shfl_xor(TT.x, off); T2.y = __shfl_xor(TT.y, off);
        T2.z = __shfl_xor(TT.z, off); T2.w = __shfl_xor(TT.w, off);
        merge4(mm, ZZ, TT, m2, Z2, T2);
      }
      const float inv = 1.f / ZZ;
      float4 S = make_float4(TT.x * inv, TT.y * inv, TT.z * inv, TT.w * inv);
      float n2 = S.x * S.x + S.y * S.y + S.z * S.z + S.w * S.w;
      n2 += __shfl_xor(n2, 1); n2 += __shfl_xor(n2, 2); n2 += __shfl_xor(n2, 4);
      const float scale = n2 / ((1.f + n2) * sqrtf(n2));
      if (it == 1) {
        if (lane < 8) {
          u_s[ss * 4 + 0] = S.x * scale; u_s[ss * 4 + 1] = S.y * scale;
          u_s[ss * 4 + 2] = S.z * scale; u_s[ss * 4 + 3] = S.w * scale;
        }
      } else {
        if (lane < 8) {
          *reinterpret_cast<float4*>(out + ((size_t)b * NC + c) * NO + ss * 4) =
              make_float4(S.x * scale, S.y * scale, S.z * scale, S.w * scale);
        }
      }
    }
    __syncthreads();
    if (it == 1) u = *reinterpret_cast<const float4*>(&u_s[sl * 4]);
  }
}

extern "C" void kernel_launch(void* const* d_in, const int* in_sizes, int n_in,
                              void* d_out, int out_size, void* d_ws, size_t ws_size,
                              hipStream_t stream) {
  const float* x = (const float*)d_in[0];
  // d_in[1] (cond) is unused by the reference computation
  const float* W = (const float*)d_in[2];
  float* out = (float*)d_out;
  float* P = (float*)d_ws;

  const size_t per_c = (size_t)NB * NR * NO * sizeof(float);  // 9.44 MB per capsule
  int nc_max = (int)(ws_size / per_c);
  if (nc_max > 8) nc_max = 8;   // keep P chunk L3-resident (<= 75.5 MB)
  if (nc_max < 1) nc_max = 1;

  for (int c0 = 0; c0 < NC; c0 += nc_max) {
    const int nc = (NC - c0 < nc_max) ? (NC - c0) : nc_max;
    k_priors<<<dim3(nc, NR / 2), 128, 0, stream>>>(x, W, P, c0);
    k_route<<<dim3(NB, nc), 512, 0, stream>>>(P, out, c0);
  }
}